// Round 10
// baseline (409.887 us; speedup 1.0000x reference)
//
#include <hip/hip_runtime.h>

#define NE 128
#define NI 32
#define NT 160   // NE + NI
#define NC 10
#define BB 512
#define LL 64
#define DD 784
#define KP 800   // K padded to 25*32 for MFMA
#define MM (BB*LL)

// ws layout (float offsets)
#define G_OFF   0
#define G_SZ    (NT*NT)              // 25600 (stored PERMUTED: see prep)
#define WH_OFF  (G_OFF + G_SZ)       // bf16 plane Wh[n][KP], 128000 ushort = 64000 floats
#define WL_OFF  (WH_OFF + 64000)     // bf16 plane Wl[n][KP]
#define U_OFF   (WL_OFF + 64000)     // 153600
#define U_SZ    (MM*NT)              // 5242880

// out layout (float offsets)
#define O_LOGITS 0
#define O_LAST   327680
#define O_RE     332800
#define O_RI     4527104
#define O_BALE   5575680
#define O_BALI   9769984

// LDS-only barrier (recur): publish ds_writes without draining vmcnt.
#define LDS_BARRIER() asm volatile("s_waitcnt lgkmcnt(0)\n\ts_barrier" ::: "memory")

typedef __attribute__((ext_vector_type(8))) short short8;
typedef __attribute__((ext_vector_type(4))) float af4;

static __device__ __forceinline__ unsigned short f2bf(float f) {   // RNE, finite inputs
  unsigned u = __float_as_uint(f);
  return (unsigned short)((u + 0x7FFFu + ((u >> 16) & 1u)) >> 16);
}
static __device__ __forceinline__ float bf2f(unsigned short h) {
  return __uint_as_float((unsigned)h << 16);
}

// Split 8 fp32 into bf16 hi/lo planes using packed HW converts (RNE, same
// rounding as f2bf).
static __device__ __forceinline__ void cvt_split8(const float* f, short8& ah, short8& al) {
  union { short8 s; unsigned u[4]; } H, L;
  #pragma unroll
  for (int p = 0; p < 4; ++p) {
    float lo = f[2*p], hi = f[2*p+1];
    unsigned h;
    asm("v_cvt_pk_bf16_f32 %0, %1, %2" : "=v"(h) : "v"(lo), "v"(hi));
    float rl = lo - __uint_as_float(h << 16);
    float rh = hi - __uint_as_float(h & 0xffff0000u);
    unsigned l;
    asm("v_cvt_pk_bf16_f32 %0, %1, %2" : "=v"(l) : "v"(rl), "v"(rh));
    H.u[p] = h; L.u[p] = l;
  }
  ah = H.s; al = L.s;
}

// ---------------------------------------------------------------------------
// Prep. G is written in a PERMUTED thread-chunk layout for recur: thread
// (kc,jc) [kc=k/20, jc=j/5] owns a contiguous 100-float chunk (400 B = 25
// aligned float4) holding G[k0+kk][j0+c] at flat index kk*5+c. This makes
// recur's per-step G re-read 25 dwordx4 per thread instead of 100 dwords.
// Input weights as split-bf16 planes Wh/Wl[n][KP] unchanged.
// ---------------------------------------------------------------------------
__global__ void prep_kernel(const float* __restrict__ Wxe, const float* __restrict__ Wxi,
                            const float* __restrict__ Wee, const float* __restrict__ Wie,
                            const float* __restrict__ Wei, const float* __restrict__ Wii,
                            float* __restrict__ ws) {
  int idx = blockIdx.x * blockDim.x + threadIdx.x;
  const int total = G_SZ + NT * KP;
  if (idx >= total) return;
  if (idx < G_SZ) {
    int k = idx / NT, j = idx % NT;
    float g;
    if (j < NE) {
      if (k < NE) g =  fmaxf(Wee[j*NE + k], 0.f);
      else        g = -fmaxf(Wie[j*NI + (k-NE)], 0.f);
    } else {
      int ji = j - NE;
      if (k < NE) g =  fmaxf(Wei[ji*NE + k], 0.f);
      else        g = -fmaxf(Wii[ji*NI + (k-NE)], 0.f);
    }
    const int dst = ((k / 20) * 32 + (j / 5)) * 100 + (k % 20) * 5 + (j % 5);
    ws[G_OFF + dst] = g;
  } else {
    int t = idx - G_SZ;
    int n = t / KP, k = t - n * KP;
    float v = 0.f;
    if (k < DD)
      v = (n < NE) ? fmaxf(Wxe[n*DD + k], 0.f) : fmaxf(Wxi[(n-NE)*DD + k], 0.f);
    unsigned short h = f2bf(v);
    unsigned short l = f2bf(v - bf2f(h));
    ((unsigned short*)(ws + WH_OFF))[t] = h;
    ((unsigned short*)(ws + WL_OFF))[t] = l;
  }
}

// ---------------------------------------------------------------------------
// GEMM v7 (unchanged, ~56 us): 2-phase LDS double-buffered MFMA GEMM.
// ---------------------------------------------------------------------------
static __device__ __forceinline__ void stage_tile(const unsigned short* __restrict__ Wh,
                                                  const unsigned short* __restrict__ Wl,
                                                  unsigned short* dstBase, int kb, int tid) {
  #pragma unroll
  for (int i = 0; i < 5; ++i) {
    const int idx = i * 256 + tid;
    const int row = idx >> 3;
    const int phys = idx & 7;
    const int logical = phys ^ (row & 7);
    const unsigned short* src =
        ((logical & 4) ? Wl : Wh) + (size_t)row * KP + kb + (logical & 3) * 8;
    __builtin_amdgcn_global_load_lds(
        (const __attribute__((address_space(1))) unsigned int*)src,
        (__attribute__((address_space(3))) unsigned int*)(dstBase + idx * 8),
        16, 0, 0);
  }
}

__global__ __launch_bounds__(256, 1) void gemm_kernel(const float* __restrict__ X,
                                                      const float* __restrict__ ws,
                                                      float* __restrict__ U) {
  __shared__ unsigned short tile[2][10240];   // 2 x 20480 B

  const int tid  = threadIdx.x;
  const int lane = tid & 63;
  const int wave = tid >> 6;
  const int n16  = lane & 15;
  const int quad = lane >> 4;
  const int sw   = n16 & 7;
  const int mbase = blockIdx.x * 128 + wave * 32;

  const unsigned short* Wh = (const unsigned short*)(ws + WH_OFF);
  const unsigned short* Wl = (const unsigned short*)(ws + WL_OFF);

  af4 acc[2][10];
  #pragma unroll
  for (int ms = 0; ms < 2; ++ms)
    #pragma unroll
    for (int nt = 0; nt < 10; ++nt)
      #pragma unroll
      for (int r = 0; r < 4; ++r) acc[ms][nt][r] = 0.f;

  const float* xr0 = X + (size_t)(mbase + n16) * DD;
  const float* xr1 = xr0 + (size_t)16 * DD;

  // ---- prologue: stage B-tile for ks=0, load A for ks=0 ----
  stage_tile(Wh, Wl, tile[0], 0, tid);
  float fa0[8], fa1[8];
  {
    const int kb = quad * 8;
    float4 v0 = *(const float4*)(xr0 + kb);
    float4 v1 = *(const float4*)(xr0 + kb + 4);
    fa0[0]=v0.x; fa0[1]=v0.y; fa0[2]=v0.z; fa0[3]=v0.w;
    fa0[4]=v1.x; fa0[5]=v1.y; fa0[6]=v1.z; fa0[7]=v1.w;
    float4 w0 = *(const float4*)(xr1 + kb);
    float4 w1 = *(const float4*)(xr1 + kb + 4);
    fa1[0]=w0.x; fa1[1]=w0.y; fa1[2]=w0.z; fa1[3]=w0.w;
    fa1[4]=w1.x; fa1[5]=w1.y; fa1[6]=w1.z; fa1[7]=w1.w;
  }
  __syncthreads();   // drains vmcnt: buf0 staged, A ready

  // ---- main loop: 25 k-steps ----
  for (int ks = 0; ks < 25; ++ks) {
    const int cur = ks & 1;
    if (ks < 24) stage_tile(Wh, Wl, tile[cur ^ 1], (ks + 1) * 32, tid);

    // A prefetch for ks+1 (masked past DD; zeros harmless, B zero-padded)
    float nf0[8] = {0,0,0,0,0,0,0,0};
    float nf1[8] = {0,0,0,0,0,0,0,0};
    {
      const int nkb = (ks + 1) * 32 + quad * 8;
      if (nkb < DD) {
        float4 v0 = *(const float4*)(xr0 + nkb);
        float4 v1 = *(const float4*)(xr0 + nkb + 4);
        nf0[0]=v0.x; nf0[1]=v0.y; nf0[2]=v0.z; nf0[3]=v0.w;
        nf0[4]=v1.x; nf0[5]=v1.y; nf0[6]=v1.z; nf0[7]=v1.w;
        float4 w0 = *(const float4*)(xr1 + nkb);
        float4 w1 = *(const float4*)(xr1 + nkb + 4);
        nf1[0]=w0.x; nf1[1]=w0.y; nf1[2]=w0.z; nf1[3]=w0.w;
        nf1[4]=w1.x; nf1[5]=w1.y; nf1[6]=w1.z; nf1[7]=w1.w;
      }
    }

    // B frags from LDS (swizzled slots)
    short8 bh[10], bl[10];
    const unsigned short* tb = tile[cur];
    #pragma unroll
    for (int nt = 0; nt < 10; ++nt) {
      const int ro = (nt * 16 + n16) * 64;              // ushort units (128 B/row)
      bh[nt] = *(const short8*)(tb + ro + ((quad ^ sw) << 3));
      bl[nt] = *(const short8*)(tb + ro + (((4 | quad) ^ sw) << 3));
    }

    short8 ah0, al0, ah1, al1;
    cvt_split8(fa0, ah0, al0);
    cvt_split8(fa1, ah1, al1);

    #pragma unroll
    for (int nt = 0; nt < 10; ++nt) {
      acc[0][nt] = __builtin_amdgcn_mfma_f32_16x16x32_bf16(ah0, bh[nt], acc[0][nt], 0, 0, 0);
      acc[1][nt] = __builtin_amdgcn_mfma_f32_16x16x32_bf16(ah1, bh[nt], acc[1][nt], 0, 0, 0);
      acc[0][nt] = __builtin_amdgcn_mfma_f32_16x16x32_bf16(ah0, bl[nt], acc[0][nt], 0, 0, 0);
      acc[1][nt] = __builtin_amdgcn_mfma_f32_16x16x32_bf16(ah1, bl[nt], acc[1][nt], 0, 0, 0);
      acc[0][nt] = __builtin_amdgcn_mfma_f32_16x16x32_bf16(al0, bh[nt], acc[0][nt], 0, 0, 0);
      acc[1][nt] = __builtin_amdgcn_mfma_f32_16x16x32_bf16(al1, bh[nt], acc[1][nt], 0, 0, 0);
    }

    #pragma unroll
    for (int j = 0; j < 8; ++j) { fa0[j] = nf0[j]; fa1[j] = nf1[j]; }

    __syncthreads();   // next buffer fully staged (all waves), reads done
  }

  // ---- epilogue: D row = quad*4 + reg, col = n16 ----
  #pragma unroll
  for (int ms = 0; ms < 2; ++ms)
    #pragma unroll
    for (int nt = 0; nt < 10; ++nt)
      #pragma unroll
      for (int r = 0; r < 4; ++r) {
        const int row = mbase + ms * 16 + quad * 4 + r;
        U[(size_t)row * NT + nt * 16 + n16] = acc[ms][nt][r];
      }
}

// ---------------------------------------------------------------------------
// Recurrent scan v7: v3 skeleton + 4-row G sharing + vector G loads.
// v3 (82 us) streams G from L2 (G=102.4KB > 32KB L1) at ~66 B/cyc/CU with
// 2 independent blocks/CU each pulling a full G copy per step. v6's LDS tier
// failed (scalar b32 + NT*4=640=0 mod 128 -> 4-way bank conflicts, 1.4e7).
// v7: 128 blocks x 256 thr, 4 batch rows per block -> one G pass serves 4
// rows (G traffic/row /4); G in permuted thread-chunk layout (see prep) so
// the per-step reload is 25 dwordx4/thread. Per-step/CU: 102.4 KB from L2
// ~= 900-1800 cyc; VALU 400 FMA + 60 shfl ~= 1000 cyc -> L2-BW-bound.
// Reload-per-step is the DESIGN (no register-residency gamble; rounds 5/7
// proved the allocator won't hold G).
// ---------------------------------------------------------------------------
__global__ __launch_bounds__(256, 1) void recur_kernel(
    const float* __restrict__ ws,
    const float* __restrict__ be, const float* __restrict__ bi,
    float* __restrict__ out) {
  __shared__ float rbuf[2][4][NT];    // [parity][row][j]
  __shared__ float balbuf[2][4][NT];
  __shared__ float biasL[NT];

  const int tid  = threadIdx.x;
  const int lane = tid & 63;
  const int wave = tid >> 6;
  const int jc   = (wave << 3) | (lane & 7);  // 0..31
  const int kc   = (lane >> 3) & 7;           // 0..7
  const int j0   = jc * 5;
  const int k0   = kc * 20;
  const int b0   = blockIdx.x * 4;

  const float* Gp = ws + G_OFF + (kc * 32 + jc) * 100;   // this thread's chunk
  const float* U  = ws + U_OFF;

  if (tid < NT) biasL[tid] = (tid < NE) ? be[tid] : bi[tid - NE];
  for (int i = tid; i < 2 * 4 * NT; i += 256) (&rbuf[0][0][0])[i] = 0.f;

  const bool owner = (kc == 0);
  float u[4][5], s[4][5];
  #pragma unroll
  for (int r = 0; r < 4; ++r)
    #pragma unroll
    for (int c = 0; c < 5; ++c) { u[r][c] = 0.f; s[r][c] = 0.f; }
  if (owner) {
    #pragma unroll
    for (int r = 0; r < 4; ++r) {
      const size_t ub = ((size_t)(b0 + r) * LL) * NT + j0;
      #pragma unroll
      for (int c = 0; c < 5; ++c) u[r][c] = U[ub + c];
    }
  }
  __syncthreads();

  for (int l = 0; l < LL; ++l) {
    const int p = l & 1;
    // ---- store step l-1 outputs (prev-parity buffers; no barrier dep) ----
    if (l > 0) {
      #pragma unroll
      for (int r = 0; r < 4; ++r) {
        const size_t ob = (size_t)(b0 + r) * LL + (l - 1);
        if (tid < NE) {
          out[O_RE   + ob * NE + tid] = rbuf[p][r][tid];
          out[O_BALE + ob * NE + tid] = balbuf[p][r][tid];
        } else if (tid < NT) {
          const int j2 = tid - NE;
          out[O_RI   + ob * NI + j2] = rbuf[p][r][NE + j2];
          out[O_BALI + ob * NI + j2] = balbuf[p][r][NE + j2];
        }
      }
    }
    // ---- prefetch next step's U (owners) ----
    float nu[4][5];
    #pragma unroll
    for (int r = 0; r < 4; ++r)
      #pragma unroll
      for (int c = 0; c < 5; ++c) nu[r][c] = 0.f;
    if (owner && l + 1 < LL) {
      #pragma unroll
      for (int r = 0; r < 4; ++r) {
        const size_t nb = ((size_t)(b0 + r) * LL + (l + 1)) * NT + j0;
        #pragma unroll
        for (int c = 0; c < 5; ++c) nu[r][c] = U[nb + c];
      }
    }
    // ---- r-vectors for 4 rows from LDS ----
    float rr[4][20];
    #pragma unroll
    for (int r = 0; r < 4; ++r)
      #pragma unroll
      for (int q = 0; q < 5; ++q) {
        float4 v = *(const float4*)(&rbuf[p][r][k0 + q * 4]);
        rr[r][q*4+0] = v.x; rr[r][q*4+1] = v.y;
        rr[r][q*4+2] = v.z; rr[r][q*4+3] = v.w;
      }
    // ---- partial dots: 25 vector G loads, each value FMA'd into 4 rows ----
    float a[4][5];
    #pragma unroll
    for (int r = 0; r < 4; ++r)
      #pragma unroll
      for (int c = 0; c < 5; ++c) a[r][c] = 0.f;
    #pragma unroll
    for (int f = 0; f < 25; ++f) {
      float4 gv = *(const float4*)(Gp + f * 4);
      const float ge[4] = {gv.x, gv.y, gv.z, gv.w};
      #pragma unroll
      for (int i = 0; i < 4; ++i) {
        const int t = f * 4 + i, kk = t / 5, c = t % 5;
        #pragma unroll
        for (int r = 0; r < 4; ++r) a[r][c] += rr[r][kk] * ge[i];
      }
    }
    // ---- butterfly reduce over kc (lane bits 3..5) ----
    #pragma unroll
    for (int r = 0; r < 4; ++r)
      #pragma unroll
      for (int c = 0; c < 5; ++c) {
        float v = a[r][c];
        v += __shfl_xor(v, 8, 64);
        v += __shfl_xor(v, 16, 64);
        v += __shfl_xor(v, 32, 64);
        a[r][c] = v;
      }
    // ---- owner lanes update state, write next-parity buffers ----
    if (owner) {
      #pragma unroll
      for (int r = 0; r < 4; ++r)
        #pragma unroll
        for (int c = 0; c < 5; ++c) {
          float bal = a[r][c] + u[r][c];
          balbuf[1 - p][r][j0 + c] = bal;
          float sn = 0.5f * (s[r][c] + bal + biasL[j0 + c]);
          s[r][c] = sn;
          rbuf[1 - p][r][j0 + c] = fmaxf(sn, 0.f);
          u[r][c] = nu[r][c];
        }
    }
    LDS_BARRIER();
  }
  // ---- final store: step 63 outputs live in parity-0 buffers ----
  #pragma unroll
  for (int r = 0; r < 4; ++r) {
    const size_t ob = (size_t)(b0 + r) * LL + 63;
    if (tid < NE) {
      out[O_RE   + ob * NE + tid] = rbuf[0][r][tid];
      out[O_BALE + ob * NE + tid] = balbuf[0][r][tid];
    } else if (tid < NT) {
      const int j2 = tid - NE;
      out[O_RI   + ob * NI + j2] = rbuf[0][r][NE + j2];
      out[O_BALI + ob * NI + j2] = balbuf[0][r][NE + j2];
    }
  }
}

// ---------------------------------------------------------------------------
// Logits v2 (MFMA, unchanged): [32768 x 128] @ Wro^T (padded to 16) + bro.
// ---------------------------------------------------------------------------
__global__ __launch_bounds__(256) void logits_kernel(const float* __restrict__ Wro,
                                                     const float* __restrict__ bro,
                                                     float* __restrict__ out) {
  __shared__ unsigned short BH[16][136];
  __shared__ unsigned short BL[16][136];
  __shared__ float broL[16];

  const int tid  = threadIdx.x;
  const int lane = tid & 63;
  const int wave = tid >> 6;
  const int n16  = lane & 15;
  const int quad = lane >> 4;

  for (int i = tid; i < 16 * NE; i += 256) {
    const int n = i >> 7, k = i & 127;
    float v = (n < NC) ? Wro[n * NE + k] : 0.f;
    unsigned short h = f2bf(v);
    BH[n][k] = h;
    BL[n][k] = f2bf(v - bf2f(h));
  }
  if (tid < 16) broL[tid] = (tid < NC) ? bro[tid] : 0.f;
  __syncthreads();

  const int mbase = blockIdx.x * 128 + wave * 32;
  const float* re = out + O_RE;

  af4 acc[2];
  #pragma unroll
  for (int ms = 0; ms < 2; ++ms)
    #pragma unroll
    for (int r = 0; r < 4; ++r) acc[ms][r] = broL[n16];

  short8 ah[2][4], al[2][4];
  #pragma unroll
  for (int ms = 0; ms < 2; ++ms) {
    const float* row = re + (size_t)(mbase + ms * 16 + n16) * NE;
    #pragma unroll
    for (int kf = 0; kf < 4; ++kf) {
      const int kb = kf * 32 + quad * 8;
      float4 v0 = *(const float4*)(row + kb);
      float4 v1 = *(const float4*)(row + kb + 4);
      float f[8] = {v0.x, v0.y, v0.z, v0.w, v1.x, v1.y, v1.z, v1.w};
      cvt_split8(f, ah[ms][kf], al[ms][kf]);
    }
  }
  short8 bh[4], bl[4];
  #pragma unroll
  for (int kf = 0; kf < 4; ++kf) {
    const int kb = kf * 32 + quad * 8;
    bh[kf] = *(const short8*)(&BH[n16][kb]);
    bl[kf] = *(const short8*)(&BL[n16][kb]);
  }
  #pragma unroll
  for (int kf = 0; kf < 4; ++kf)
    #pragma unroll
    for (int ms = 0; ms < 2; ++ms) {
      acc[ms] = __builtin_amdgcn_mfma_f32_16x16x32_bf16(ah[ms][kf], bh[kf], acc[ms], 0, 0, 0);
      acc[ms] = __builtin_amdgcn_mfma_f32_16x16x32_bf16(ah[ms][kf], bl[kf], acc[ms], 0, 0, 0);
      acc[ms] = __builtin_amdgcn_mfma_f32_16x16x32_bf16(al[ms][kf], bh[kf], acc[ms], 0, 0, 0);
    }

  if (n16 < NC) {
    #pragma unroll
    for (int ms = 0; ms < 2; ++ms)
      #pragma unroll
      for (int r = 0; r < 4; ++r) {
        const int m = mbase + ms * 16 + quad * 4 + r;
        out[O_LOGITS + (size_t)m * NC + n16] = acc[ms][r];
        if ((m & 63) == 63)
          out[O_LAST + (size_t)(m >> 6) * NC + n16] = acc[ms][r];
      }
  }
}

extern "C" void kernel_launch(void* const* d_in, const int* in_sizes, int n_in,
                              void* d_out, int out_size, void* d_ws, size_t ws_size,
                              hipStream_t stream) {
  const float* x   = (const float*)d_in[0];
  const float* Wxe = (const float*)d_in[1];
  const float* Wxi = (const float*)d_in[2];
  const float* Wee = (const float*)d_in[3];
  const float* Wie = (const float*)d_in[4];
  const float* Wei = (const float*)d_in[5];
  const float* Wii = (const float*)d_in[6];
  const float* be  = (const float*)d_in[7];
  const float* bi  = (const float*)d_in[8];
  const float* Wro = (const float*)d_in[9];
  const float* bro = (const float*)d_in[10];
  float* ws  = (float*)d_ws;
  float* out = (float*)d_out;

  hipLaunchKernelGGL(prep_kernel, dim3((G_SZ + NT*KP + 255)/256), dim3(256), 0, stream,
                     Wxe, Wxi, Wee, Wie, Wei, Wii, ws);
  hipLaunchKernelGGL(gemm_kernel, dim3(MM/128), dim3(256), 0, stream,
                     x, ws, ws + U_OFF);
  hipLaunchKernelGGL(recur_kernel, dim3(BB/4), dim3(256), 0, stream,
                     ws, be, bi, out);
  hipLaunchKernelGGL(logits_kernel, dim3(MM/128), dim3(256), 0, stream,
                     Wro, bro, out);
}

// Round 11
// 357.847 us; speedup vs baseline: 1.1454x; 1.1454x over previous
//
#include <hip/hip_runtime.h>

#define NE 128
#define NI 32
#define NT 160   // NE + NI
#define NC 10
#define BB 512
#define LL 64
#define DD 784
#define KP 800   // K padded to 25*32 for MFMA
#define MM (BB*LL)

// ws layout (float offsets)
#define G_OFF   0
#define G_SZ    (NT*NT)              // 25600 (stored PERMUTED: see prep)
#define WH_OFF  (G_OFF + G_SZ)       // bf16 plane Wh[n][KP], 128000 ushort = 64000 floats
#define WL_OFF  (WH_OFF + 64000)     // bf16 plane Wl[n][KP]
#define U_OFF   (WL_OFF + 64000)     // 153600
#define U_SZ    (MM*NT)              // 5242880

// out layout (float offsets)
#define O_LOGITS 0
#define O_LAST   327680
#define O_RE     332800
#define O_RI     4527104
#define O_BALE   5575680
#define O_BALI   9769984

// LDS-only barrier (recur): publish ds_writes without draining vmcnt.
#define LDS_BARRIER() asm volatile("s_waitcnt lgkmcnt(0)\n\ts_barrier" ::: "memory")

typedef __attribute__((ext_vector_type(8))) short short8;
typedef __attribute__((ext_vector_type(4))) float af4;

static __device__ __forceinline__ unsigned short f2bf(float f) {   // RNE, finite inputs
  unsigned u = __float_as_uint(f);
  return (unsigned short)((u + 0x7FFFu + ((u >> 16) & 1u)) >> 16);
}
static __device__ __forceinline__ float bf2f(unsigned short h) {
  return __uint_as_float((unsigned)h << 16);
}

// Split 8 fp32 into bf16 hi/lo planes using packed HW converts (RNE, same
// rounding as f2bf).
static __device__ __forceinline__ void cvt_split8(const float* f, short8& ah, short8& al) {
  union { short8 s; unsigned u[4]; } H, L;
  #pragma unroll
  for (int p = 0; p < 4; ++p) {
    float lo = f[2*p], hi = f[2*p+1];
    unsigned h;
    asm("v_cvt_pk_bf16_f32 %0, %1, %2" : "=v"(h) : "v"(lo), "v"(hi));
    float rl = lo - __uint_as_float(h << 16);
    float rh = hi - __uint_as_float(h & 0xffff0000u);
    unsigned l;
    asm("v_cvt_pk_bf16_f32 %0, %1, %2" : "=v"(l) : "v"(rl), "v"(rh));
    H.u[p] = h; L.u[p] = l;
  }
  ah = H.s; al = L.s;
}

// ---------------------------------------------------------------------------
// Prep. G stored PERMUTED (unchanged from round 9, correctness-verified):
// thread (kc=k/20, jc=j/5) owns a contiguous 100-float chunk at
// ((kc*32+jc)*100 + (k%20)*5 + (j%5)). recur v8 stages it linearly into LDS
// and each thread b128-reads its own chunk.
// ---------------------------------------------------------------------------
__global__ void prep_kernel(const float* __restrict__ Wxe, const float* __restrict__ Wxi,
                            const float* __restrict__ Wee, const float* __restrict__ Wie,
                            const float* __restrict__ Wei, const float* __restrict__ Wii,
                            float* __restrict__ ws) {
  int idx = blockIdx.x * blockDim.x + threadIdx.x;
  const int total = G_SZ + NT * KP;
  if (idx >= total) return;
  if (idx < G_SZ) {
    int k = idx / NT, j = idx % NT;
    float g;
    if (j < NE) {
      if (k < NE) g =  fmaxf(Wee[j*NE + k], 0.f);
      else        g = -fmaxf(Wie[j*NI + (k-NE)], 0.f);
    } else {
      int ji = j - NE;
      if (k < NE) g =  fmaxf(Wei[ji*NE + k], 0.f);
      else        g = -fmaxf(Wii[ji*NI + (k-NE)], 0.f);
    }
    const int dst = ((k / 20) * 32 + (j / 5)) * 100 + (k % 20) * 5 + (j % 5);
    ws[G_OFF + dst] = g;
  } else {
    int t = idx - G_SZ;
    int n = t / KP, k = t - n * KP;
    float v = 0.f;
    if (k < DD)
      v = (n < NE) ? fmaxf(Wxe[n*DD + k], 0.f) : fmaxf(Wxi[(n-NE)*DD + k], 0.f);
    unsigned short h = f2bf(v);
    unsigned short l = f2bf(v - bf2f(h));
    ((unsigned short*)(ws + WH_OFF))[t] = h;
    ((unsigned short*)(ws + WL_OFF))[t] = l;
  }
}

// ---------------------------------------------------------------------------
// GEMM v7 (unchanged, ~56 us): 2-phase LDS double-buffered MFMA GEMM.
// ---------------------------------------------------------------------------
static __device__ __forceinline__ void stage_tile(const unsigned short* __restrict__ Wh,
                                                  const unsigned short* __restrict__ Wl,
                                                  unsigned short* dstBase, int kb, int tid) {
  #pragma unroll
  for (int i = 0; i < 5; ++i) {
    const int idx = i * 256 + tid;
    const int row = idx >> 3;
    const int phys = idx & 7;
    const int logical = phys ^ (row & 7);
    const unsigned short* src =
        ((logical & 4) ? Wl : Wh) + (size_t)row * KP + kb + (logical & 3) * 8;
    __builtin_amdgcn_global_load_lds(
        (const __attribute__((address_space(1))) unsigned int*)src,
        (__attribute__((address_space(3))) unsigned int*)(dstBase + idx * 8),
        16, 0, 0);
  }
}

__global__ __launch_bounds__(256, 1) void gemm_kernel(const float* __restrict__ X,
                                                      const float* __restrict__ ws,
                                                      float* __restrict__ U) {
  __shared__ unsigned short tile[2][10240];   // 2 x 20480 B

  const int tid  = threadIdx.x;
  const int lane = tid & 63;
  const int wave = tid >> 6;
  const int n16  = lane & 15;
  const int quad = lane >> 4;
  const int sw   = n16 & 7;
  const int mbase = blockIdx.x * 128 + wave * 32;

  const unsigned short* Wh = (const unsigned short*)(ws + WH_OFF);
  const unsigned short* Wl = (const unsigned short*)(ws + WL_OFF);

  af4 acc[2][10];
  #pragma unroll
  for (int ms = 0; ms < 2; ++ms)
    #pragma unroll
    for (int nt = 0; nt < 10; ++nt)
      #pragma unroll
      for (int r = 0; r < 4; ++r) acc[ms][nt][r] = 0.f;

  const float* xr0 = X + (size_t)(mbase + n16) * DD;
  const float* xr1 = xr0 + (size_t)16 * DD;

  // ---- prologue: stage B-tile for ks=0, load A for ks=0 ----
  stage_tile(Wh, Wl, tile[0], 0, tid);
  float fa0[8], fa1[8];
  {
    const int kb = quad * 8;
    float4 v0 = *(const float4*)(xr0 + kb);
    float4 v1 = *(const float4*)(xr0 + kb + 4);
    fa0[0]=v0.x; fa0[1]=v0.y; fa0[2]=v0.z; fa0[3]=v0.w;
    fa0[4]=v1.x; fa0[5]=v1.y; fa0[6]=v1.z; fa0[7]=v1.w;
    float4 w0 = *(const float4*)(xr1 + kb);
    float4 w1 = *(const float4*)(xr1 + kb + 4);
    fa1[0]=w0.x; fa1[1]=w0.y; fa1[2]=w0.z; fa1[3]=w0.w;
    fa1[4]=w1.x; fa1[5]=w1.y; fa1[6]=w1.z; fa1[7]=w1.w;
  }
  __syncthreads();   // drains vmcnt: buf0 staged, A ready

  // ---- main loop: 25 k-steps ----
  for (int ks = 0; ks < 25; ++ks) {
    const int cur = ks & 1;
    if (ks < 24) stage_tile(Wh, Wl, tile[cur ^ 1], (ks + 1) * 32, tid);

    // A prefetch for ks+1 (masked past DD; zeros harmless, B zero-padded)
    float nf0[8] = {0,0,0,0,0,0,0,0};
    float nf1[8] = {0,0,0,0,0,0,0,0};
    {
      const int nkb = (ks + 1) * 32 + quad * 8;
      if (nkb < DD) {
        float4 v0 = *(const float4*)(xr0 + nkb);
        float4 v1 = *(const float4*)(xr0 + nkb + 4);
        nf0[0]=v0.x; nf0[1]=v0.y; nf0[2]=v0.z; nf0[3]=v0.w;
        nf0[4]=v1.x; nf0[5]=v1.y; nf0[6]=v1.z; nf0[7]=v1.w;
        float4 w0 = *(const float4*)(xr1 + nkb);
        float4 w1 = *(const float4*)(xr1 + nkb + 4);
        nf1[0]=w0.x; nf1[1]=w0.y; nf1[2]=w0.z; nf1[3]=w0.w;
        nf1[4]=w1.x; nf1[5]=w1.y; nf1[6]=w1.z; nf1[7]=w1.w;
      }
    }

    // B frags from LDS (swizzled slots)
    short8 bh[10], bl[10];
    const unsigned short* tb = tile[cur];
    #pragma unroll
    for (int nt = 0; nt < 10; ++nt) {
      const int ro = (nt * 16 + n16) * 64;              // ushort units (128 B/row)
      bh[nt] = *(const short8*)(tb + ro + ((quad ^ sw) << 3));
      bl[nt] = *(const short8*)(tb + ro + (((4 | quad) ^ sw) << 3));
    }

    short8 ah0, al0, ah1, al1;
    cvt_split8(fa0, ah0, al0);
    cvt_split8(fa1, ah1, al1);

    #pragma unroll
    for (int nt = 0; nt < 10; ++nt) {
      acc[0][nt] = __builtin_amdgcn_mfma_f32_16x16x32_bf16(ah0, bh[nt], acc[0][nt], 0, 0, 0);
      acc[1][nt] = __builtin_amdgcn_mfma_f32_16x16x32_bf16(ah1, bh[nt], acc[1][nt], 0, 0, 0);
      acc[0][nt] = __builtin_amdgcn_mfma_f32_16x16x32_bf16(ah0, bl[nt], acc[0][nt], 0, 0, 0);
      acc[1][nt] = __builtin_amdgcn_mfma_f32_16x16x32_bf16(ah1, bl[nt], acc[1][nt], 0, 0, 0);
      acc[0][nt] = __builtin_amdgcn_mfma_f32_16x16x32_bf16(al0, bh[nt], acc[0][nt], 0, 0, 0);
      acc[1][nt] = __builtin_amdgcn_mfma_f32_16x16x32_bf16(al1, bh[nt], acc[1][nt], 0, 0, 0);
    }

    #pragma unroll
    for (int j = 0; j < 8; ++j) { fa0[j] = nf0[j]; fa1[j] = nf1[j]; }

    __syncthreads();   // next buffer fully staged (all waves), reads done
  }

  // ---- epilogue: D row = quad*4 + reg, col = n16 ----
  #pragma unroll
  for (int ms = 0; ms < 2; ++ms)
    #pragma unroll
    for (int nt = 0; nt < 10; ++nt)
      #pragma unroll
      for (int r = 0; r < 4; ++r) {
        const int row = mbase + ms * 16 + quad * 4 + r;
        U[(size_t)row * NT + nt * 16 + n16] = acc[ms][nt][r];
      }
}

// ---------------------------------------------------------------------------
// Recurrent scan v8: LDS-tier G, conflict-free by construction.
// Post-mortems: v3 (82us) = L2-BW bound (2 blocks/CU x full-G/step at ~66
// B/cyc). v6 LDS failed on access pattern (scalar b32, 640 B row stride ->
// 4-way bank conflicts). v7 failed on GLOBAL coalescing (per-thread-chunk
// layout -> 64 cache lines per instruction).
// v8: stage the PERMUTED G (v7 layout, correctness-verified) linearly into
// dynamic LDS once (coalesced float4 copy), then per step each thread
// b128-reads its contiguous 400 B chunk: bank start = (jc*4+4f) mod 32 ->
// 8 lanes per 4-bank group x 8 groups = 128 B/cyc (LDS peak). 256 blocks x
// 256 thr (1 block/CU, all CUs), 2 rows/block share each G read.
// Step ~= max(LDS 800-1200 cyc, VALU ~600) -> predict ~30 us.
// ---------------------------------------------------------------------------
__global__ __launch_bounds__(256, 1) void recur_kernel(
    const float* __restrict__ ws,
    const float* __restrict__ be, const float* __restrict__ bi,
    float* __restrict__ out) {
  extern __shared__ float Gs[];       // 25600 floats = 102400 B dynamic
  __shared__ float rbuf[2][2][NT];    // [parity][row][j]
  __shared__ float balbuf[2][2][NT];
  __shared__ float biasL[NT];

  const int tid  = threadIdx.x;
  const int lane = tid & 63;
  const int wave = tid >> 6;
  const int jc   = (wave << 3) | (lane & 7);  // 0..31
  const int kc   = (lane >> 3) & 7;           // 0..7
  const int j0   = jc * 5;
  const int k0   = kc * 20;
  const int b0   = blockIdx.x * 2;

  const float* U = ws + U_OFF;
  const float* Gp = Gs + (kc * 32 + jc) * 100;   // this thread's LDS chunk

  // stage permuted G into LDS: linear coalesced float4 copy (once)
  for (int i = tid; i < G_SZ / 4; i += 256)
    ((float4*)Gs)[i] = ((const float4*)(ws + G_OFF))[i];

  if (tid < NT) biasL[tid] = (tid < NE) ? be[tid] : bi[tid - NE];
  for (int i = tid; i < 2 * 2 * NT; i += 256) (&rbuf[0][0][0])[i] = 0.f;

  const bool owner = (kc == 0);
  float u[2][5], s[2][5];
  #pragma unroll
  for (int r = 0; r < 2; ++r)
    #pragma unroll
    for (int c = 0; c < 5; ++c) { u[r][c] = 0.f; s[r][c] = 0.f; }
  if (owner) {
    #pragma unroll
    for (int r = 0; r < 2; ++r) {
      const size_t ub = ((size_t)(b0 + r) * LL) * NT + j0;
      #pragma unroll
      for (int c = 0; c < 5; ++c) u[r][c] = U[ub + c];
    }
  }
  __syncthreads();   // G staged, buffers zeroed

  for (int l = 0; l < LL; ++l) {
    const int p = l & 1;
    // ---- store step l-1 outputs (prev-parity buffers; no barrier dep) ----
    if (l > 0) {
      #pragma unroll
      for (int r = 0; r < 2; ++r) {
        const size_t ob = (size_t)(b0 + r) * LL + (l - 1);
        if (tid < NE) {
          out[O_RE   + ob * NE + tid] = rbuf[p][r][tid];
          out[O_BALE + ob * NE + tid] = balbuf[p][r][tid];
        } else if (tid < NT) {
          const int j2 = tid - NE;
          out[O_RI   + ob * NI + j2] = rbuf[p][r][NE + j2];
          out[O_BALI + ob * NI + j2] = balbuf[p][r][NE + j2];
        }
      }
    }
    // ---- prefetch next step's U (owners) ----
    float nu[2][5];
    #pragma unroll
    for (int r = 0; r < 2; ++r)
      #pragma unroll
      for (int c = 0; c < 5; ++c) nu[r][c] = 0.f;
    if (owner && l + 1 < LL) {
      #pragma unroll
      for (int r = 0; r < 2; ++r) {
        const size_t nb = ((size_t)(b0 + r) * LL + (l + 1)) * NT + j0;
        #pragma unroll
        for (int c = 0; c < 5; ++c) nu[r][c] = U[nb + c];
      }
    }
    // ---- r-vectors for 2 rows from LDS ----
    float rr[2][20];
    #pragma unroll
    for (int r = 0; r < 2; ++r)
      #pragma unroll
      for (int q = 0; q < 5; ++q) {
        float4 v = *(const float4*)(&rbuf[p][r][k0 + q * 4]);
        rr[r][q*4+0] = v.x; rr[r][q*4+1] = v.y;
        rr[r][q*4+2] = v.z; rr[r][q*4+3] = v.w;
      }
    // ---- partial dots: 25 b128 LDS reads, each value FMA'd into 2 rows ----
    float a[2][5];
    #pragma unroll
    for (int r = 0; r < 2; ++r)
      #pragma unroll
      for (int c = 0; c < 5; ++c) a[r][c] = 0.f;
    #pragma unroll
    for (int f = 0; f < 25; ++f) {
      float4 gv = *(const float4*)(Gp + f * 4);
      const float ge[4] = {gv.x, gv.y, gv.z, gv.w};
      #pragma unroll
      for (int i = 0; i < 4; ++i) {
        const int t = f * 4 + i, kk = t / 5, c = t % 5;
        #pragma unroll
        for (int r = 0; r < 2; ++r) a[r][c] += rr[r][kk] * ge[i];
      }
    }
    // ---- butterfly reduce over kc (lane bits 3..5) ----
    #pragma unroll
    for (int r = 0; r < 2; ++r)
      #pragma unroll
      for (int c = 0; c < 5; ++c) {
        float v = a[r][c];
        v += __shfl_xor(v, 8, 64);
        v += __shfl_xor(v, 16, 64);
        v += __shfl_xor(v, 32, 64);
        a[r][c] = v;
      }
    // ---- owner lanes update state, write next-parity buffers ----
    if (owner) {
      #pragma unroll
      for (int r = 0; r < 2; ++r)
        #pragma unroll
        for (int c = 0; c < 5; ++c) {
          float bal = a[r][c] + u[r][c];
          balbuf[1 - p][r][j0 + c] = bal;
          float sn = 0.5f * (s[r][c] + bal + biasL[j0 + c]);
          s[r][c] = sn;
          rbuf[1 - p][r][j0 + c] = fmaxf(sn, 0.f);
          u[r][c] = nu[r][c];
        }
    }
    LDS_BARRIER();
  }
  // ---- final store: step 63 outputs live in parity-0 buffers ----
  #pragma unroll
  for (int r = 0; r < 2; ++r) {
    const size_t ob = (size_t)(b0 + r) * LL + 63;
    if (tid < NE) {
      out[O_RE   + ob * NE + tid] = rbuf[0][r][tid];
      out[O_BALE + ob * NE + tid] = balbuf[0][r][tid];
    } else if (tid < NT) {
      const int j2 = tid - NE;
      out[O_RI   + ob * NI + j2] = rbuf[0][r][NE + j2];
      out[O_BALI + ob * NI + j2] = balbuf[0][r][NE + j2];
    }
  }
}

// ---------------------------------------------------------------------------
// Logits v2 (MFMA, unchanged): [32768 x 128] @ Wro^T (padded to 16) + bro.
// ---------------------------------------------------------------------------
__global__ __launch_bounds__(256) void logits_kernel(const float* __restrict__ Wro,
                                                     const float* __restrict__ bro,
                                                     float* __restrict__ out) {
  __shared__ unsigned short BH[16][136];
  __shared__ unsigned short BL[16][136];
  __shared__ float broL[16];

  const int tid  = threadIdx.x;
  const int lane = tid & 63;
  const int wave = tid >> 6;
  const int n16  = lane & 15;
  const int quad = lane >> 4;

  for (int i = tid; i < 16 * NE; i += 256) {
    const int n = i >> 7, k = i & 127;
    float v = (n < NC) ? Wro[n * NE + k] : 0.f;
    unsigned short h = f2bf(v);
    BH[n][k] = h;
    BL[n][k] = f2bf(v - bf2f(h));
  }
  if (tid < 16) broL[tid] = (tid < NC) ? bro[tid] : 0.f;
  __syncthreads();

  const int mbase = blockIdx.x * 128 + wave * 32;
  const float* re = out + O_RE;

  af4 acc[2];
  #pragma unroll
  for (int ms = 0; ms < 2; ++ms)
    #pragma unroll
    for (int r = 0; r < 4; ++r) acc[ms][r] = broL[n16];

  short8 ah[2][4], al[2][4];
  #pragma unroll
  for (int ms = 0; ms < 2; ++ms) {
    const float* row = re + (size_t)(mbase + ms * 16 + n16) * NE;
    #pragma unroll
    for (int kf = 0; kf < 4; ++kf) {
      const int kb = kf * 32 + quad * 8;
      float4 v0 = *(const float4*)(row + kb);
      float4 v1 = *(const float4*)(row + kb + 4);
      float f[8] = {v0.x, v0.y, v0.z, v0.w, v1.x, v1.y, v1.z, v1.w};
      cvt_split8(f, ah[ms][kf], al[ms][kf]);
    }
  }
  short8 bh[4], bl[4];
  #pragma unroll
  for (int kf = 0; kf < 4; ++kf) {
    const int kb = kf * 32 + quad * 8;
    bh[kf] = *(const short8*)(&BH[n16][kb]);
    bl[kf] = *(const short8*)(&BL[n16][kb]);
  }
  #pragma unroll
  for (int kf = 0; kf < 4; ++kf)
    #pragma unroll
    for (int ms = 0; ms < 2; ++ms) {
      acc[ms] = __builtin_amdgcn_mfma_f32_16x16x32_bf16(ah[ms][kf], bh[kf], acc[ms], 0, 0, 0);
      acc[ms] = __builtin_amdgcn_mfma_f32_16x16x32_bf16(ah[ms][kf], bl[kf], acc[ms], 0, 0, 0);
      acc[ms] = __builtin_amdgcn_mfma_f32_16x16x32_bf16(al[ms][kf], bh[kf], acc[ms], 0, 0, 0);
    }

  if (n16 < NC) {
    #pragma unroll
    for (int ms = 0; ms < 2; ++ms)
      #pragma unroll
      for (int r = 0; r < 4; ++r) {
        const int m = mbase + ms * 16 + quad * 4 + r;
        out[O_LOGITS + (size_t)m * NC + n16] = acc[ms][r];
        if ((m & 63) == 63)
          out[O_LAST + (size_t)(m >> 6) * NC + n16] = acc[ms][r];
      }
  }
}

extern "C" void kernel_launch(void* const* d_in, const int* in_sizes, int n_in,
                              void* d_out, int out_size, void* d_ws, size_t ws_size,
                              hipStream_t stream) {
  const float* x   = (const float*)d_in[0];
  const float* Wxe = (const float*)d_in[1];
  const float* Wxi = (const float*)d_in[2];
  const float* Wee = (const float*)d_in[3];
  const float* Wie = (const float*)d_in[4];
  const float* Wei = (const float*)d_in[5];
  const float* Wii = (const float*)d_in[6];
  const float* be  = (const float*)d_in[7];
  const float* bi  = (const float*)d_in[8];
  const float* Wro = (const float*)d_in[9];
  const float* bro = (const float*)d_in[10];
  float* ws  = (float*)d_ws;
  float* out = (float*)d_out;

  hipLaunchKernelGGL(prep_kernel, dim3((G_SZ + NT*KP + 255)/256), dim3(256), 0, stream,
                     Wxe, Wxi, Wee, Wie, Wei, Wii, ws);
  hipLaunchKernelGGL(gemm_kernel, dim3(MM/128), dim3(256), 0, stream,
                     x, ws, ws + U_OFF);
  hipLaunchKernelGGL(recur_kernel, dim3(BB/2), dim3(256), G_SZ * sizeof(float), stream,
                     ws, be, bi, out);
  hipLaunchKernelGGL(logits_kernel, dim3(MM/128), dim3(256), 0, stream,
                     Wro, bro, out);
}